// Round 4
// baseline (134.780 us; speedup 1.0000x reference)
//
#include <hip/hip_runtime.h>
#include <hip/hip_cooperative_groups.h>
#include <cstddef>

// Problem: b=2,h=16,L=4096,d=16,dv=64, chunk=256. Second-order linear attn.
#define BH    32
#define LSEQ  4096
#define D     16
#define DV    64
#define CS    256
#define NC    16
#define NF    160     // padded feature dim (153 real)
#define NZ    65      // 64 v cols + z col
#define KSTEPS 5      // NF/32
#define PER   (NZ * NF)   // 10400 state elems per (bh, chunk)

typedef short short8 __attribute__((ext_vector_type(8)));
typedef float f32x4 __attribute__((ext_vector_type(4)));
typedef float f4 __attribute__((ext_vector_type(4)));
typedef unsigned uint4v __attribute__((ext_vector_type(4)));

// ws layout (bytes) — kbf/vt regions kept for the fallback path only
#define OFF_KBF 0u                                    // [BH][LSEQ][16] bf16  (4 MiB)
#define OFF_VT  (4u*1024u*1024u)                      // [BH][NZ][LSEQ] bf16 (fallback only)
#define OFF_ST  (OFF_VT + (unsigned)(BH*NZ*LSEQ*2))  // [BH][NC][NZ][NF] bf16 (10.65 MB)
#define OFF_FLG (OFF_ST + (unsigned)(BH*NC*PER*2))   // [BH*NC][8] u32 flags (16 KB)

__device__ __forceinline__ unsigned f2bf(float x) {
  unsigned u = __float_as_uint(x);
  return (u + 0x7FFFu + ((u >> 16) & 1u)) >> 16;   // RNE; inputs always finite
}
__device__ __forceinline__ float bf2f(unsigned short u) {
  return __uint_as_float(((unsigned)u) << 16);
}
__device__ __forceinline__ short8 zero8() {
  short8 z = {0,0,0,0,0,0,0,0};
  return z;
}
// packed f32x2 -> bf16x2 (RNE, same result as f2bf pair), 1 VALU op
__device__ __forceinline__ unsigned cvtpk(float lo, float hi) {
  unsigned r;
  asm("v_cvt_pk_bf16_f32 %0, %1, %2" : "=v"(r) : "v"(lo), "v"(hi));
  return r;
}
__device__ __forceinline__ short8 pk4(unsigned a, unsigned b, unsigned c, unsigned d) {
  uint4v u = {a, b, c, d};
  return __builtin_bit_cast(short8, u);
}

// feature table: d | (e<<8) | (psi_half?1<<16:0).  qx/kx rows have [16]=1, [17]=0.
__device__ __forceinline__ unsigned feat_tbl(int f) {
  if (f == 0)  return 16u | (16u << 8);                       // const: 1*1
  if (f <= 16) return (unsigned)(f - 1) | (16u << 8);         // linear: x_d * 1
  if (f < 137) {                                              // pairs d<e
    int p = f - 17, off = 0;
    for (int d = 0; d < 15; ++d) {
      int cnt = 15 - d;
      if (p < off + cnt) return (unsigned)d | ((unsigned)(d + 1 + p - off) << 8);
      off += cnt;
    }
  }
  if (f < 153) {                                              // diag: psi=0.5*q_d^2, chi=k_d^2
    int d = f - 137;
    return (unsigned)d | ((unsigned)d << 8) | (1u << 16);
  }
  return 17u | (17u << 8);                                    // pad: 0*0
}

// =================== UNIFIED cooperative kernel ===================
// 512 blocks x 512 threads, 2 blocks/CU.
// R4: the mid-kernel grid barrier is replaced by per-(block,wave) release/
// acquire flags — block (bh,c) waits only for the 8 producer waves of each of
// chunks 0..c-1 of ITS bh. Cooperative launch is kept purely for guaranteed
// co-residency (spin-wait safety) + one START-of-kernel grid sync that
// publishes the flag resets (no work precedes it -> no convoy slack).
struct Smem {
  float kxqx[CS][18];                                   // 18432 B (kx pre-wait, qx post)
  __align__(16) unsigned short vt[NZ][264];             // 34320 B (pre-wait only)
  union {
    __align__(16) unsigned short stt[NZ][168];          // 21840 B (B / inter)
    struct {
      __align__(16) unsigned short ptile[8][640];       // 10240 B (intra, 16 rows/wave)
      float zline[CS];                                  // 1024 B (epilogue)
    } u;
  } b;
  unsigned tbl[NF];                                     // 640 B
};                                                      // total 75232 B

__global__ __launch_bounds__(512, 4) void unified(const float* __restrict__ q,
                                                  const float* __restrict__ k,
                                                  const float* __restrict__ v,
                                                  unsigned* __restrict__ kbf_u32,
                                                  unsigned short* __restrict__ st,
                                                  unsigned* __restrict__ flags,
                                                  float* __restrict__ out) {
  __shared__ Smem sm;
  int blk = blockIdx.x, bh = blk >> 4, c = blk & 15;
  int t = threadIdx.x, w = t >> 6, lane = t & 63, quad = lane >> 4, n16 = lane & 15;
  const size_t base = (size_t)bh * LSEQ + (size_t)c * CS;
  (void)kbf_u32;  // fallback-path buffer; unused here

  // ---- flag reset (own block's 8 wave-flags) + publishing grid sync ----
  if (t < 8)
    __hip_atomic_store(&flags[blk * 8 + t], 0u, __ATOMIC_RELAXED,
                       __HIP_MEMORY_SCOPE_AGENT);
  cooperative_groups::this_grid().sync();   // start-of-kernel: no convoy slack

  // strip assignment: waves 0,1 (which carry 2 state tiles) get light strips.
  // w0:{0,1} w1:{2,3} w2:{4,15} w3:{5,14} w4:{6,13} w5:{7,12} w6:{8,11} w7:{9,10}
  const int s0 = (w < 2) ? 2 * w : (w + 2);
  const int s1 = (w < 2) ? 2 * w + 1 : (17 - w);

  // -------- Q fragments: global -> registers (for intra QK^T)
  short8 qf[2] = {zero8(), zero8()};
  if (quad < 2) {
#pragma unroll
    for (int mm = 0; mm < 2; ++mm) {
      int s = mm ? s1 : s0;
      const f4* qp = (const f4*)(q + (base + (size_t)(s * 16 + n16)) * D + quad * 8);
      f4 qa = qp[0] * 0.25f;
      f4 qb = qp[1] * 0.25f;
      qf[mm] = pk4(cvtpk(qa[0], qa[1]), cvtpk(qa[2], qa[3]),
                   cvtpk(qb[0], qb[1]), cvtpk(qb[2], qb[3]));
    }
  }

  // ---------------- Phase A: stage k (fp32 LDS), v^T (bf16 LDS) ----------------
  {
    const f4* K4 = (const f4*)(k + base * D);
    for (int idx = t; idx < 1024; idx += 512) {
      f4 kv = K4[idx];
      float* dst = &sm.kxqx[idx >> 2][(idx & 3) * 4];
      *(float2*)dst = make_float2(kv[0], kv[1]);
      *(float2*)(dst + 2) = make_float2(kv[2], kv[3]);
    }
    for (int i = t; i < CS; i += 512)
      *(float2*)&sm.kxqx[i][16] = make_float2(1.f, 0.f);
    const f4* V4 = (const f4*)(v + base * DV);
    for (int idx = t; idx < 2048; idx += 512) {
      int m16 = idx & 15, j0 = (idx >> 4) * 2;
      f4 a  = V4[j0 * 16 + m16];
      f4 bq = V4[j0 * 16 + 16 + m16];
#pragma unroll
      for (int r = 0; r < 4; ++r)
        *(unsigned*)&sm.vt[m16 * 4 + r][j0] = cvtpk(a[r], bq[r]);
    }
    if (t < 128) ((unsigned*)&sm.vt[64][0])[t] = 0x3F803F80u;      // ones column
    if (t < NF) sm.tbl[t] = feat_tbl(t);
  }
  __syncthreads();

  // ---------------- state MFMA + store + per-wave release (skip c==15) --------
  // waves 0,1 own feature-tiles {w, w+8}; waves 2..7 own tile {w}.
  if (c < 15) {
    const int ntt = (w < 2) ? 2 : 1;
    unsigned short* stc = st + (size_t)(bh * NC + c) * PER;
    for (int tt = 0; tt < ntt; ++tt) {
      const int T = tt ? (w + 8) : w;
      unsigned tv = sm.tbl[T * 16 + n16];
      int d0 = tv & 255, e0 = (tv >> 8) & 255;
      f32x4 acc5[5];
#pragma unroll
      for (int nt = 0; nt < 5; ++nt) acc5[nt] = (f32x4){0.f, 0.f, 0.f, 0.f};
      for (int jt = 0; jt < 8; ++jt) {
        float x[8];
#pragma unroll
        for (int i = 0; i < 8; ++i) {
          const float* kr = &sm.kxqx[jt * 32 + quad * 8 + i][0];
          x[i] = kr[d0] * kr[e0];                        // chi (0.5 folded at store)
        }
        short8 afr = pk4(cvtpk(x[0], x[1]), cvtpk(x[2], x[3]),
                         cvtpk(x[4], x[5]), cvtpk(x[6], x[7]));
#pragma unroll
        for (int nt = 0; nt < 5; ++nt) {
          int ncol = nt * 16 + n16;
          short8 b = zero8();
          if (ncol < NZ) b = *(const short8*)(&sm.vt[ncol][jt * 32 + quad * 8]);
          acc5[nt] = __builtin_amdgcn_mfma_f32_16x16x32_bf16(afr, b, acc5[nt], 0, 0, 0);
        }
      }
      const int feat0 = T * 16 + quad * 4;
      float sc[4];
#pragma unroll
      for (int r = 0; r < 4; ++r)
        sc[r] = (feat0 + r >= 137 && feat0 + r < 153) ? 0.5f : 1.0f;  // psi-diag fold
#pragma unroll
      for (int nt = 0; nt < 5; ++nt) {
        int col = nt * 16 + n16;
        if (col < NZ) {
          unsigned lo = cvtpk(acc5[nt][0] * sc[0], acc5[nt][1] * sc[1]);
          unsigned hi = cvtpk(acc5[nt][2] * sc[2], acc5[nt][3] * sc[3]);
          *(uint2*)(stc + (size_t)col * NF + feat0) = make_uint2(lo, hi);
        }
      }
    }
    // per-wave release: this wave's state tile(s) are globally visible,
    // then publish. Wave-lockstep guarantees all lanes' fences complete
    // before lane 0's store issues.
    __threadfence();
    if (lane == 0)
      __hip_atomic_store(&flags[blk * 8 + w], 1u, __ATOMIC_RELEASE,
                         __HIP_MEMORY_SCOPE_AGENT);
  }

  // ---------------- intra (independent of other blocks) ----------------
  f32x4 accC[2][5];
#pragma unroll
  for (int mm = 0; mm < 2; ++mm)
#pragma unroll
    for (int nt = 0; nt < 5; ++nt) accC[mm][nt] = (f32x4){0.f, 0.f, 0.f, 0.f};

  {
    unsigned short* pw = &sm.b.u.ptile[w][0];
    short8 ones;
#pragma unroll
    for (int i = 0; i < 8; ++i) ones[i] = (short)0x3F80;

#pragma unroll
    for (int mm = 0; mm < 2; ++mm) {
      const int s = mm ? s1 : s0;
      const int ntiles = (s >> 1) + 1;
      for (int jt = 0; jt < ntiles; ++jt) {
        short8 kb[2];
#pragma unroll
        for (int ntk = 0; ntk < 2; ++ntk) {
          short8 b = zero8();
          if (quad < 2) {
            const float2* kr =
                (const float2*)&sm.kxqx[jt * 32 + ntk * 16 + n16][quad * 8];
            float2 k0 = kr[0], k1 = kr[1], k2 = kr[2], k3 = kr[3];
            b = pk4(cvtpk(k0.x, k0.y), cvtpk(k1.x, k1.y),
                    cvtpk(k2.x, k2.y), cvtpk(k3.x, k3.y));
          }
          kb[ntk] = b;
        }
        f32x4 zf = (f32x4){0.f, 0.f, 0.f, 0.f};
        f32x4 sres[2];
        sres[0] = __builtin_amdgcn_mfma_f32_16x16x32_bf16(qf[mm], kb[0], zf, 0, 0, 0);
        sres[1] = __builtin_amdgcn_mfma_f32_16x16x32_bf16(qf[mm], kb[1], zf, 0, 0, 0);
        const bool last = (jt == ntiles - 1);
#pragma unroll
        for (int ntk = 0; ntk < 2; ++ntk) {
          float ph[4];
#pragma unroll
          for (int r = 0; r < 4; ++r) {
            float sv = sres[ntk][r];
            float phi = fmaf(sv, fmaf(0.5f, sv, 1.0f), 1.0f);  // 1 + s + 0.5 s^2
            if (last) {
              int qrow_g = s * 16 + quad * 4 + r;
              int kcol_g = jt * 32 + ntk * 16 + n16;
              if (kcol_g > qrow_g) phi = 0.f;                  // causal
            }
            ph[r] = phi;
          }
          unsigned u01 = cvtpk(ph[0], ph[1]);
          unsigned u23 = cvtpk(ph[2], ph[3]);
          int rb = (quad * 4) * 40 + ntk * 16 + n16;
          pw[rb      ] = (unsigned short)u01;
          pw[rb +  40] = (unsigned short)(u01 >> 16);
          pw[rb +  80] = (unsigned short)u23;
          pw[rb + 120] = (unsigned short)(u23 >> 16);
        }
        short8 pa = *(const short8*)(pw + n16 * 40 + quad * 8);
#pragma unroll
        for (int nt = 0; nt < 5; ++nt) {
          int ncol = nt * 16 + n16;
          short8 b;
          if (ncol < 64)       b = *(const short8*)(&sm.vt[ncol][jt * 32 + quad * 8]);
          else if (ncol == 64) b = ones;
          else                 b = zero8();
          accC[mm][nt] = __builtin_amdgcn_mfma_f32_16x16x32_bf16(pa, b, accC[mm][nt], 0, 0, 0);
        }
      }
    }
  }
  __syncthreads();   // kx (state+intra) fully consumed -> safe to overwrite with qx

  // qx load issued before the wait: global q latency hides under the spin
  {
    const f4* Q4 = (const f4*)(q + base * D);
    for (int idx = t; idx < 1024; idx += 512) {
      f4 qv = Q4[idx] * 0.25f;                           // d^-0.5; cols 16/17 persist
      float* dst = &sm.kxqx[idx >> 2][(idx & 3) * 4];
      *(float2*)dst = make_float2(qv[0], qv[1]);
      *(float2*)(dst + 2) = make_float2(qv[2], qv[3]);
    }
  }

  // ---------------- acquire: wait for chunks 0..c-1 of THIS bh ----------------
  if (c > 0) {
    if (t < 8 * c) {
      const unsigned* fp = &flags[(bh * 16 + (t >> 3)) * 8 + (t & 7)];
      while (__hip_atomic_load(fp, __ATOMIC_RELAXED, __HIP_MEMORY_SCOPE_AGENT) == 0u)
        __builtin_amdgcn_s_sleep(8);
    }
    __syncthreads();
    __threadfence();   // acquire side: order subsequent st reads
  } else {
    __syncthreads();   // qx-store ordering for inter/epilogue path symmetry
  }

  // ---------------- Phase B: pipelined prefix sum into LDS ----------------
  if (c > 0) {
    const unsigned short* stg = st + (size_t)bh * NC * PER;
    float sa0[8], sa1[8], sa2[8];
#pragma unroll
    for (int e = 0; e < 8; ++e) { sa0[e] = 0.f; sa1[e] = 0.f; sa2[e] = 0.f; }
    const int i0 = t * 8, i1 = i0 + 4096, i2 = i0 + 8192;
    const bool h2 = (i2 < PER);
    short8 a0 = *(const short8*)(stg + i0);
    short8 a1 = *(const short8*)(stg + i1);
    short8 a2 = h2 ? *(const short8*)(stg + i2) : zero8();
    for (int cc = 1; cc < c; ++cc) {
      const unsigned short* pn = stg + (size_t)cc * PER;
      short8 b0 = *(const short8*)(pn + i0);             // next-iter loads issued
      short8 b1 = *(const short8*)(pn + i1);             // before current adds ->
      short8 b2 = h2 ? *(const short8*)(pn + i2) : zero8();  // latency overlapped
#pragma unroll
      for (int e = 0; e < 8; ++e) {
        sa0[e] += bf2f((unsigned short)a0[e]);
        sa1[e] += bf2f((unsigned short)a1[e]);
        sa2[e] += bf2f((unsigned short)a2[e]);
      }
      a0 = b0; a1 = b1; a2 = b2;
    }
#pragma unroll
    for (int e = 0; e < 8; ++e) {
      sa0[e] += bf2f((unsigned short)a0[e]);
      sa1[e] += bf2f((unsigned short)a1[e]);
      sa2[e] += bf2f((unsigned short)a2[e]);
    }
    {
      int col = i0 / NF, ft = i0 - col * NF;
      *(short8*)(&sm.b.stt[col][ft]) =
          pk4(cvtpk(sa0[0], sa0[1]), cvtpk(sa0[2], sa0[3]),
              cvtpk(sa0[4], sa0[5]), cvtpk(sa0[6], sa0[7]));
      col = i1 / NF; ft = i1 - col * NF;
      *(short8*)(&sm.b.stt[col][ft]) =
          pk4(cvtpk(sa1[0], sa1[1]), cvtpk(sa1[2], sa1[3]),
              cvtpk(sa1[4], sa1[5]), cvtpk(sa1[6], sa1[7]));
      if (h2) {
        col = i2 / NF; ft = i2 - col * NF;
        *(short8*)(&sm.b.stt[col][ft]) =
            pk4(cvtpk(sa2[0], sa2[1]), cvtpk(sa2[2], sa2[3]),
                cvtpk(sa2[4], sa2[5]), cvtpk(sa2[6], sa2[7]));
      }
    }
  }
  __syncthreads();

  // ---------------- inter: acc += psi(Q) · S_prefix ----------------
  if (c > 0) {
    const float* qrow0 = &sm.kxqx[s0 * 16 + n16][0];
    const float* qrow1 = &sm.kxqx[s1 * 16 + n16][0];
    for (int ks = 0; ks < KSTEPS; ++ks) {
      unsigned tvv[8];
#pragma unroll
      for (int i = 0; i < 8; ++i) tvv[i] = sm.tbl[ks * 32 + quad * 8 + i];
      float x0[8], x1[8];
#pragma unroll
      for (int i = 0; i < 8; ++i) {
        int d = tvv[i] & 255, e = (tvv[i] >> 8) & 255;
        x0[i] = qrow0[d] * qrow0[e];
        x1[i] = qrow1[d] * qrow1[e];
      }
      short8 afr0 = pk4(cvtpk(x0[0], x0[1]), cvtpk(x0[2], x0[3]),
                        cvtpk(x0[4], x0[5]), cvtpk(x0[6], x0[7]));
      short8 afr1 = pk4(cvtpk(x1[0], x1[1]), cvtpk(x1[2], x1[3]),
                        cvtpk(x1[4], x1[5]), cvtpk(x1[6], x1[7]));
#pragma unroll
      for (int nt = 0; nt < 5; ++nt) {
        int ncol = nt * 16 + n16;
        short8 b = zero8();
        if (ncol < NZ) b = *(const short8*)(&sm.b.stt[ncol][ks * 32 + quad * 8]);
        accC[0][nt] = __builtin_amdgcn_mfma_f32_16x16x32_bf16(afr0, b, accC[0][nt], 0, 0, 0);
        accC[1][nt] = __builtin_amdgcn_mfma_f32_16x16x32_bf16(afr1, b, accC[1][nt], 0, 0, 0);
      }
    }
  }
  __syncthreads();   // stt fully consumed -> zline (aliasing) may be written

  // epilogue: z broadcast via per-wave LDS rows, normalize, store
  if (n16 == 0) {
#pragma unroll
    for (int mm = 0; mm < 2; ++mm) {
      int s = mm ? s1 : s0;
#pragma unroll
      for (int r = 0; r < 4; ++r)
        sm.b.u.zline[s * 16 + quad * 4 + r] = accC[mm][4][r];
    }
  }
  float* oc = out + base * DV;
#pragma unroll
  for (int mm = 0; mm < 2; ++mm) {
    int s = mm ? s1 : s0;
#pragma unroll
    for (int r = 0; r < 4; ++r) {
      int qrow = s * 16 + quad * 4 + r;
      float inv = __builtin_amdgcn_rcpf(sm.b.u.zline[qrow] + 1e-6f);
#pragma unroll
      for (int nt = 0; nt < 4; ++nt)
        oc[(size_t)qrow * DV + nt * 16 + n16] = accC[mm][nt][r] * inv;
    }
  }
}

// =================== FALLBACK: proven R5 3-kernel path ===================
__global__ __launch_bounds__(320) void pass_a(const float* __restrict__ k,
                                              const float* __restrict__ v,
                                              unsigned* __restrict__ kbf_u32,
                                              unsigned* __restrict__ vt_u32,
                                              unsigned short* __restrict__ st) {
  __shared__ float kx[CS][18];
  __shared__ __align__(16) unsigned short vt_lds[NZ][264];
  __shared__ unsigned tbl[NF];
  int blk = blockIdx.x, bh = blk >> 4, c = blk & 15;
  int t = threadIdx.x, w = t >> 6, lane = t & 63, quad = lane >> 4, n16 = lane & 15;
  {
    const float2* kc2 = (const float2*)(k + ((size_t)bh * LSEQ + c * CS) * D);
    unsigned* kbd = kbf_u32 + ((size_t)bh * LSEQ + c * CS) * D / 2;
    for (int i = t; i < 2048; i += 320) {
      float2 v2 = kc2[i];
      kbd[i] = f2bf(v2.x) | (f2bf(v2.y) << 16);
      int j = i >> 3, dd = (i & 7) * 2;
      kx[j][dd] = v2.x; kx[j][dd + 1] = v2.y;
    }
    for (int i = t; i < CS; i += 320) { kx[i][16] = 1.f; kx[i][17] = 0.f; }
  }
  {
    const float* vb = v + ((size_t)bh * LSEQ + c * CS) * DV;
    for (int i = t; i < CS * DV; i += 320) {
      int j = i >> 6, f = i & 63;
      vt_lds[f][j] = (unsigned short)f2bf(vb[i]);
    }
    for (int i = t; i < CS; i += 320) vt_lds[64][i] = (unsigned short)0x3F80;
  }
  if (t < NF) tbl[t] = feat_tbl(t);
  __syncthreads();
  {
    unsigned* vtg = vt_u32 + (size_t)bh * NZ * (LSEQ / 2) + c * (CS / 2);
    for (int i = t; i < NZ * (CS / 2); i += 320) {
      int f = i >> 7, jp = (i & 127) * 2;
      vtg[(size_t)f * (LSEQ / 2) + (i & 127)] =
          (unsigned)vt_lds[f][jp] | ((unsigned)vt_lds[f][jp + 1] << 16);
    }
  }
  f32x4 acc[2][5];
#pragma unroll
  for (int mm = 0; mm < 2; ++mm)
#pragma unroll
    for (int nt = 0; nt < 5; ++nt) acc[mm][nt] = (f32x4){0.f, 0.f, 0.f, 0.f};
  for (int jt = 0; jt < 8; ++jt) {
    short8 afr[2];
#pragma unroll
    for (int mm = 0; mm < 2; ++mm) {
      int feat = (w * 2 + mm) * 16 + n16;
      unsigned tv = tbl[feat];
      int d = tv & 255, e = (tv >> 8) & 255;
      short8 a;
#pragma unroll
      for (int i = 0; i < 8; ++i) {
        int jj = jt * 32 + quad * 8 + i;
        a[i] = (short)f2bf(kx[jj][d] * kx[jj][e]);
      }
      afr[mm] = a;
    }
#pragma unroll
    for (int nt = 0; nt < 5; ++nt) {
      int ncol = nt * 16 + n16;
      short8 b = zero8();
      if (ncol < NZ) b = *(const short8*)(&vt_lds[ncol][jt * 32 + quad * 8]);
      acc[0][nt] = __builtin_amdgcn_mfma_f32_16x16x32_bf16(afr[0], b, acc[0][nt], 0, 0, 0);
      acc[1][nt] = __builtin_amdgcn_mfma_f32_16x16x32_bf16(afr[1], b, acc[1][nt], 0, 0, 0);
    }
  }
  unsigned short* stc = st + (size_t)(bh * NC + c) * PER;
#pragma unroll
  for (int mm = 0; mm < 2; ++mm)
#pragma unroll
    for (int nt = 0; nt < 5; ++nt) {
      int col = nt * 16 + n16;
      if (col < NZ) {
        unsigned lo = f2bf(acc[mm][nt][0]) | (f2bf(acc[mm][nt][1]) << 16);
        unsigned hi = f2bf(acc[mm][nt][2]) | (f2bf(acc[mm][nt][3]) << 16);
        int feat0 = (w * 2 + mm) * 16 + quad * 4;
        *(uint2*)(stc + (size_t)col * NF + feat0) = make_uint2(lo, hi);
      }
    }
}

__global__ __launch_bounds__(256) void pass_b(unsigned short* __restrict__ st) {
  const int TOT = BH * PER;
  int idx = blockIdx.x * 256 + threadIdx.x;
  if (idx >= TOT) return;
  int bh = idx / PER, r = idx - bh * PER;
  unsigned short* p = st + (size_t)bh * NC * PER + r;
  float run = 0.f;
#pragma unroll
  for (int c = 0; c < NC; ++c) {
    unsigned short uv = p[(size_t)c * PER];
    float val = bf2f(uv);
    p[(size_t)c * PER] = (unsigned short)f2bf(run);
    run += val;
  }
}

__global__ __launch_bounds__(512) void pass_c(const float* __restrict__ q,
                                              const unsigned short* __restrict__ kbf,
                                              const unsigned short* __restrict__ vt,
                                              const unsigned short* __restrict__ st,
                                              float* __restrict__ out) {
  __shared__ float qx[CS][18];
  __shared__ unsigned tbl[NF];
  __shared__ __align__(16) unsigned short ptile[8][32 * 40];
  __shared__ float zline[CS];
  int blk = blockIdx.x, bh = blk >> 4, c = blk & 15;
  const size_t base = (size_t)bh * LSEQ + (size_t)c * CS;
  const float* qc = q + base * D;
  int t = threadIdx.x, w = t >> 6, lane = t & 63, quad = lane >> 4, n16 = lane & 15;
  for (int i = t; i < CS * D; i += 512) {
    int row = i >> 4, dd = i & 15;
    qx[row][dd] = qc[i] * 0.25f;
  }
  for (int i = t; i < CS; i += 512) { qx[i][16] = 1.f; qx[i][17] = 0.f; }
  if (t < NF) tbl[t] = feat_tbl(t);
  __syncthreads();
  f32x4 acc[2][5];
#pragma unroll
  for (int mm = 0; mm < 2; ++mm)
#pragma unroll
    for (int nt = 0; nt < 5; ++nt) acc[mm][nt] = (f32x4){0.f, 0.f, 0.f, 0.f};
  if (c > 0) {
    const unsigned short* stc = st + (size_t)(bh * NC + c) * PER;
    for (int ks = 0; ks < KSTEPS; ++ks) {
      short8 afr[2];
#pragma unroll
      for (int mm = 0; mm < 2; ++mm) {
        const float* qrow = qx[(w * 2 + mm) * 16 + n16];
        short8 a;
#pragma unroll
        for (int i = 0; i < 8; ++i) {
          int f = ks * 32 + quad * 8 + i;
          unsigned tv = tbl[f];
          float val = qrow[tv & 255] * qrow[(tv >> 8) & 255];
          if (tv & 0x10000u) val *= 0.5f;
          a[i] = (short)f2bf(val);
        }
        afr[mm] = a;
      }
#pragma unroll
      for (int nt = 0; nt < 5; ++nt) {
        int ncol = nt * 16 + n16;
        short8 b = zero8();
        if (ncol < NZ) b = *(const short8*)(stc + (size_t)ncol * NF + ks * 32 + quad * 8);
        acc[0][nt] = __builtin_amdgcn_mfma_f32_16x16x32_bf16(afr[0], b, acc[0][nt], 0, 0, 0);
        acc[1][nt] = __builtin_amdgcn_mfma_f32_16x16x32_bf16(afr[1], b, acc[1][nt], 0, 0, 0);
      }
    }
  }
  short8 qfr[2];
#pragma unroll
  for (int mm = 0; mm < 2; ++mm) {
    int m = (w * 2 + mm) * 16 + n16;
    short8 a = zero8();
    if (quad < 2) {
#pragma unroll
      for (int i = 0; i < 8; ++i) a[i] = (short)f2bf(qx[m][quad * 8 + i]);
    }
    qfr[mm] = a;
  }
  const unsigned short* kbc = kbf + base * D;
  const unsigned short* vtb = vt + (size_t)bh * NZ * LSEQ + (size_t)c * CS;
  unsigned short* pw = &ptile[w][0];
  short8 ones;
#pragma unroll
  for (int i = 0; i < 8; ++i) ones[i] = (short)0x3F80;
  for (int jt = 0; jt <= w; ++jt) {
    short8 kb[2];
#pragma unroll
    for (int ntk = 0; ntk < 2; ++ntk) {
      short8 b = zero8();
      if (quad < 2)
        b = *(const short8*)(kbc + (size_t)(jt * 32 + ntk * 16 + n16) * D + quad * 8);
      kb[ntk] = b;
    }
    f32x4 zf = (f32x4){0.f, 0.f, 0.f, 0.f};
    f32x4 s[2][2];
#pragma unroll
    for (int mm = 0; mm < 2; ++mm)
#pragma unroll
      for (int ntk = 0; ntk < 2; ++ntk)
        s[mm][ntk] = __builtin_amdgcn_mfma_f32_16x16x32_bf16(qfr[mm], kb[ntk], zf, 0, 0, 0);
    bool diag = (jt == w);
#pragma unroll
    for (int mm = 0; mm < 2; ++mm)
#pragma unroll
      for (int ntk = 0; ntk < 2; ++ntk)
#pragma unroll
        for (int r = 0; r < 4; ++r) {
          float sv = s[mm][ntk][r];
          float phi = fmaf(0.5f * sv, sv, sv) + 1.0f;
          if (diag) {
            int qrow = mm * 16 + quad * 4 + r;
            int kcol = ntk * 16 + n16;
            if (kcol > qrow) phi = 0.f;
          }
          pw[(mm * 16 + quad * 4 + r) * 40 + ntk * 16 + n16] = (unsigned short)f2bf(phi);
        }
    short8 pa[2];
#pragma unroll
    for (int mm = 0; mm < 2; ++mm)
      pa[mm] = *(const short8*)(pw + (mm * 16 + n16) * 40 + quad * 8);
#pragma unroll
    for (int nt = 0; nt < 5; ++nt) {
      int ncol = nt * 16 + n16;
      short8 b;
      if (ncol < 64)       b = *(const short8*)(vtb + (size_t)ncol * LSEQ + jt * 32 + quad * 8);
      else if (ncol == 64) b = ones;
      else                 b = zero8();
      acc[0][nt] = __builtin_amdgcn_mfma_f32_16x16x32_bf16(pa[0], b, acc[0][nt], 0, 0, 0);
      acc[1][nt] = __builtin_amdgcn_mfma_f32_16x16x32_bf16(pa[1], b, acc[1][nt], 0, 0, 0);
    }
  }
  if (n16 == 0) {
#pragma unroll
    for (int mm = 0; mm < 2; ++mm)
#pragma unroll
      for (int r = 0; r < 4; ++r)
        zline[(w * 2 + mm) * 16 + quad * 4 + r] = acc[mm][4][r];
  }
  float* oc = out + base * DV;
#pragma unroll
  for (int mm = 0; mm < 2; ++mm)
#pragma unroll
    for (int r = 0; r < 4; ++r) {
      int qrow = (w * 2 + mm) * 16 + quad * 4 + r;
      float inv = 1.0f / (zline[qrow] + 1e-6f);
#pragma unroll
      for (int nt = 0; nt < 4; ++nt)
        oc[(size_t)qrow * DV + nt * 16 + n16] = acc[mm][nt][r] * inv;
    }
}

extern "C" void kernel_launch(void* const* d_in, const int* in_sizes, int n_in,
                              void* d_out, int out_size, void* d_ws, size_t ws_size,
                              hipStream_t stream) {
  (void)in_sizes; (void)n_in; (void)out_size; (void)ws_size;
  const float* q = (const float*)d_in[0];
  const float* k = (const float*)d_in[1];
  const float* v = (const float*)d_in[2];
  float* out = (float*)d_out;
  char* wsb = (char*)d_ws;
  unsigned*       kbf32 = (unsigned*)(wsb + OFF_KBF);
  unsigned short* kbf   = (unsigned short*)(wsb + OFF_KBF);
  unsigned*       vt32  = (unsigned*)(wsb + OFF_VT);
  unsigned short* vtp   = (unsigned short*)(wsb + OFF_VT);
  unsigned short* stp   = (unsigned short*)(wsb + OFF_ST);
  unsigned*       flg   = (unsigned*)(wsb + OFF_FLG);

  // deterministic per-call path choice (same result every call -> capture-safe)
  int nb = 0;
  hipError_t oe = hipOccupancyMaxActiveBlocksPerMultiprocessor(
      &nb, reinterpret_cast<const void*>(unified), 512, 0);
  if (oe == hipSuccess && nb >= 2) {
    void* args[] = {(void*)&q, (void*)&k, (void*)&v,
                    (void*)&kbf32, (void*)&stp, (void*)&flg, (void*)&out};
    hipLaunchCooperativeKernel(reinterpret_cast<const void*>(unified),
                               dim3(BH * NC), dim3(512), args, 0, stream);
  } else {
    pass_a<<<BH * NC, 320, 0, stream>>>(k, v, kbf32, vt32, stp);
    pass_b<<<1300, 256, 0, stream>>>(stp);
    pass_c<<<BH * NC, 512, 0, stream>>>(q, kbf, vtp, stp, out);
  }
}

// Round 5
// 126.365 us; speedup vs baseline: 1.0666x; 1.0666x over previous
//
#include <hip/hip_runtime.h>
#include <cstddef>

// Problem: b=2,h=16,L=4096,d=16,dv=64, chunk=256. Second-order linear attn.
#define BH    32
#define LSEQ  4096
#define D     16
#define DV    64
#define CS    256
#define NC    16
#define NF    160     // padded feature dim (153 real)
#define NZ    65      // 64 v cols + z col
#define KSTEPS 5      // NF/32
#define PER   (NZ * NF)   // 10400 state elems per (bh, chunk)

typedef short short8 __attribute__((ext_vector_type(8)));
typedef float f32x4 __attribute__((ext_vector_type(4)));
typedef float f4 __attribute__((ext_vector_type(4)));
typedef unsigned uint4v __attribute__((ext_vector_type(4)));

// ws layout (bytes)
#define OFF_KBF 0u                                    // [BH][LSEQ][16] bf16  (4 MiB)
#define OFF_ST  (4u*1024u*1024u)                      // [BH][NC][NZ][NF] bf16 (10.65 MB)

__device__ __forceinline__ float bf2f(unsigned short u) {
  return __uint_as_float(((unsigned)u) << 16);
}
__device__ __forceinline__ short8 zero8() {
  short8 z = {0,0,0,0,0,0,0,0};
  return z;
}
// packed f32x2 -> bf16x2 (RNE), 1 VALU op
__device__ __forceinline__ unsigned cvtpk(float lo, float hi) {
  unsigned r;
  asm("v_cvt_pk_bf16_f32 %0, %1, %2" : "=v"(r) : "v"(lo), "v"(hi));
  return r;
}
__device__ __forceinline__ short8 pk4(unsigned a, unsigned b, unsigned c, unsigned d) {
  uint4v u = {a, b, c, d};
  return __builtin_bit_cast(short8, u);
}

// feature table: d | (e<<8) | (psi_half?1<<16:0).  qx/kx rows have [16]=1, [17]=0.
__device__ __forceinline__ unsigned feat_tbl(int f) {
  if (f == 0)  return 16u | (16u << 8);                       // const: 1*1
  if (f <= 16) return (unsigned)(f - 1) | (16u << 8);         // linear: x_d * 1
  if (f < 137) {                                              // pairs d<e
    int p = f - 17, off = 0;
    for (int d = 0; d < 15; ++d) {
      int cnt = 15 - d;
      if (p < off + cnt) return (unsigned)d | ((unsigned)(d + 1 + p - off) << 8);
      off += cnt;
    }
  }
  if (f < 153) {                                              // diag: psi=0.5*q_d^2, chi=k_d^2
    int d = f - 137;
    return (unsigned)d | ((unsigned)d << 8) | (1u << 16);
  }
  return 17u | (17u << 8);                                    // pad: 0*0
}

// ============ PASS 1: stage k (kbf bf16 global + fp32 LDS), v^T; state ============
// bh = blk & 31, c = blk >> 5  ->  blk % 8 == bh % 8: all chunks of a bh share an
// XCD, so st/kbf writes here are L2-local for pass2's reads of the same bh.
// c == 15: kbf only (its state is never consumed).
__global__ __launch_bounds__(512, 4) void pass1(const float* __restrict__ k,
                                                const float* __restrict__ v,
                                                unsigned* __restrict__ kbf_u32,
                                                unsigned short* __restrict__ st) {
  __shared__ float kx[CS][18];
  __shared__ __align__(16) unsigned short vt[NZ][264];
  __shared__ unsigned tbl[NF];
  int blk = blockIdx.x, bh = blk & 31, c = blk >> 5;
  int t = threadIdx.x, w = t >> 6, lane = t & 63, quad = lane >> 4, n16 = lane & 15;
  const size_t base = (size_t)bh * LSEQ + (size_t)c * CS;
  (void)lane;

  {
    const f4* K4 = (const f4*)(k + base * D);
    uint2* kbd2 = (uint2*)(kbf_u32 + base * D / 2);
    for (int idx = t; idx < 1024; idx += 512) {
      f4 kv = K4[idx];
      kbd2[idx] = make_uint2(cvtpk(kv[0], kv[1]), cvtpk(kv[2], kv[3]));
      float* dst = &kx[idx >> 2][(idx & 3) * 4];
      *(float2*)dst = make_float2(kv[0], kv[1]);
      *(float2*)(dst + 2) = make_float2(kv[2], kv[3]);
    }
    for (int i = t; i < CS; i += 512) { kx[i][16] = 1.f; kx[i][17] = 0.f; }
  }
  if (c < 15) {
    const f4* V4 = (const f4*)(v + base * DV);
    for (int idx = t; idx < 2048; idx += 512) {
      int m16 = idx & 15, j0 = (idx >> 4) * 2;
      f4 a  = V4[j0 * 16 + m16];
      f4 bq = V4[j0 * 16 + 16 + m16];
#pragma unroll
      for (int r = 0; r < 4; ++r)
        *(unsigned*)&vt[m16 * 4 + r][j0] = cvtpk(a[r], bq[r]);
    }
    if (t < 128) ((unsigned*)&vt[64][0])[t] = 0x3F803F80u;       // ones column
  }
  if (t < NF) tbl[t] = feat_tbl(t);
  __syncthreads();

  if (c < 15) {
    // waves 0,1 own feature-tiles {w, w+8}; waves 2..7 own tile {w}. (10 tiles)
    const int ntt = (w < 2) ? 2 : 1;
    unsigned short* stc = st + (size_t)(bh * NC + c) * PER;
    for (int tt = 0; tt < ntt; ++tt) {
      const int T = tt ? (w + 8) : w;
      unsigned tv = tbl[T * 16 + n16];
      int d0 = tv & 255, e0 = (tv >> 8) & 255;
      f32x4 acc5[5];
#pragma unroll
      for (int nt = 0; nt < 5; ++nt) acc5[nt] = (f32x4){0.f, 0.f, 0.f, 0.f};
      for (int jt = 0; jt < 8; ++jt) {
        float x[8];
#pragma unroll
        for (int i = 0; i < 8; ++i) {
          const float* kr = &kx[jt * 32 + quad * 8 + i][0];
          x[i] = kr[d0] * kr[e0];                        // chi (0.5 folded at store)
        }
        short8 afr = pk4(cvtpk(x[0], x[1]), cvtpk(x[2], x[3]),
                         cvtpk(x[4], x[5]), cvtpk(x[6], x[7]));
#pragma unroll
        for (int nt = 0; nt < 5; ++nt) {
          int ncol = nt * 16 + n16;
          short8 b = zero8();
          if (ncol < NZ) b = *(const short8*)(&vt[ncol][jt * 32 + quad * 8]);
          acc5[nt] = __builtin_amdgcn_mfma_f32_16x16x32_bf16(afr, b, acc5[nt], 0, 0, 0);
        }
      }
      const int feat0 = T * 16 + quad * 4;
      float sc[4];
#pragma unroll
      for (int r = 0; r < 4; ++r)
        sc[r] = (feat0 + r >= 137 && feat0 + r < 153) ? 0.5f : 1.0f;  // psi-diag fold
#pragma unroll
      for (int nt = 0; nt < 5; ++nt) {
        int col = nt * 16 + n16;
        if (col < NZ) {
          unsigned lo = cvtpk(acc5[nt][0] * sc[0], acc5[nt][1] * sc[1]);
          unsigned hi = cvtpk(acc5[nt][2] * sc[2], acc5[nt][3] * sc[3]);
          *(uint2*)(stc + (size_t)col * NF + feat0) = make_uint2(lo, hi);
        }
      }
    }
  }
}

// ============ PASS 2: B (prefix) + inter + intra + epilogue ============
// Kernel boundary = the global barrier (replaces cooperative grid.sync).
struct Smem2 {
  float qx[CS][18];                                     // 18432 B
  __align__(16) unsigned short vt[NZ][264];             // 34320 B
  union {
    __align__(16) unsigned short stt[NZ][168];          // 21840 B (B / inter)
    struct {
      __align__(16) unsigned short ptile[8][640];       // 10240 B (intra)
      float zline[CS];                                  // 1024 B (epilogue)
    } u;
  } b;
  unsigned tbl[NF];                                     // 640 B
};                                                      // total 75232 B

__global__ __launch_bounds__(512, 4) void pass2(const float* __restrict__ q,
                                                const unsigned short* __restrict__ kbf,
                                                const float* __restrict__ v,
                                                const unsigned short* __restrict__ st,
                                                float* __restrict__ out) {
  __shared__ Smem2 sm;
  int blk = blockIdx.x, bh = blk & 31, c = blk >> 5;
  int t = threadIdx.x, w = t >> 6, lane = t & 63, quad = lane >> 4, n16 = lane & 15;
  const size_t base = (size_t)bh * LSEQ + (size_t)c * CS;

  // strip assignment (balanced intra): w0:{0,1} w1:{2,3} w2:{4,15} ... w7:{9,10}
  const int s0 = (w < 2) ? 2 * w : (w + 2);
  const int s1 = (w < 2) ? 2 * w + 1 : (17 - w);

  // Q fragments: global -> registers (for intra QK^T)
  short8 qf[2] = {zero8(), zero8()};
  if (quad < 2) {
#pragma unroll
    for (int mm = 0; mm < 2; ++mm) {
      int s = mm ? s1 : s0;
      const f4* qp = (const f4*)(q + (base + (size_t)(s * 16 + n16)) * D + quad * 8);
      f4 qa = qp[0] * 0.25f;
      f4 qb = qp[1] * 0.25f;
      qf[mm] = pk4(cvtpk(qa[0], qa[1]), cvtpk(qa[2], qa[3]),
                   cvtpk(qb[0], qb[1]), cvtpk(qb[2], qb[3]));
    }
  }

  // stage qx (fp32 LDS, *0.25), v^T (bf16 LDS), tbl
  {
    const f4* Q4 = (const f4*)(q + base * D);
    for (int idx = t; idx < 1024; idx += 512) {
      f4 qv = Q4[idx] * 0.25f;
      float* dst = &sm.qx[idx >> 2][(idx & 3) * 4];
      *(float2*)dst = make_float2(qv[0], qv[1]);
      *(float2*)(dst + 2) = make_float2(qv[2], qv[3]);
    }
    for (int i = t; i < CS; i += 512) { sm.qx[i][16] = 1.f; sm.qx[i][17] = 0.f; }
    const f4* V4 = (const f4*)(v + base * DV);
    for (int idx = t; idx < 2048; idx += 512) {
      int m16 = idx & 15, j0 = (idx >> 4) * 2;
      f4 a  = V4[j0 * 16 + m16];
      f4 bq = V4[j0 * 16 + 16 + m16];
#pragma unroll
      for (int r = 0; r < 4; ++r)
        *(unsigned*)&sm.vt[m16 * 4 + r][j0] = cvtpk(a[r], bq[r]);
    }
    if (t < 128) ((unsigned*)&sm.vt[64][0])[t] = 0x3F803F80u;    // ones column
    if (t < NF) sm.tbl[t] = feat_tbl(t);
  }
  __syncthreads();

  // ---------------- Phase B: pipelined prefix sum into LDS ----------------
  if (c > 0) {
    const unsigned short* stg = st + (size_t)bh * NC * PER;
    float sa0[8], sa1[8], sa2[8];
#pragma unroll
    for (int e = 0; e < 8; ++e) { sa0[e] = 0.f; sa1[e] = 0.f; sa2[e] = 0.f; }
    const int i0 = t * 8, i1 = i0 + 4096, i2 = i0 + 8192;
    const bool h2 = (i2 < PER);
    short8 a0 = *(const short8*)(stg + i0);
    short8 a1 = *(const short8*)(stg + i1);
    short8 a2 = h2 ? *(const short8*)(stg + i2) : zero8();
    for (int cc = 1; cc < c; ++cc) {
      const unsigned short* pn = stg + (size_t)cc * PER;
      short8 b0 = *(const short8*)(pn + i0);             // next-iter loads issued
      short8 b1 = *(const short8*)(pn + i1);             // before current adds
      short8 b2 = h2 ? *(const short8*)(pn + i2) : zero8();
#pragma unroll
      for (int e = 0; e < 8; ++e) {
        sa0[e] += bf2f((unsigned short)a0[e]);
        sa1[e] += bf2f((unsigned short)a1[e]);
        sa2[e] += bf2f((unsigned short)a2[e]);
      }
      a0 = b0; a1 = b1; a2 = b2;
    }
#pragma unroll
    for (int e = 0; e < 8; ++e) {
      sa0[e] += bf2f((unsigned short)a0[e]);
      sa1[e] += bf2f((unsigned short)a1[e]);
      sa2[e] += bf2f((unsigned short)a2[e]);
    }
    {
      int col = i0 / NF, ft = i0 - col * NF;
      *(short8*)(&sm.b.stt[col][ft]) =
          pk4(cvtpk(sa0[0], sa0[1]), cvtpk(sa0[2], sa0[3]),
              cvtpk(sa0[4], sa0[5]), cvtpk(sa0[6], sa0[7]));
      col = i1 / NF; ft = i1 - col * NF;
      *(short8*)(&sm.b.stt[col][ft]) =
          pk4(cvtpk(sa1[0], sa1[1]), cvtpk(sa1[2], sa1[3]),
              cvtpk(sa1[4], sa1[5]), cvtpk(sa1[6], sa1[7]));
      if (h2) {
        col = i2 / NF; ft = i2 - col * NF;
        *(short8*)(&sm.b.stt[col][ft]) =
            pk4(cvtpk(sa2[0], sa2[1]), cvtpk(sa2[2], sa2[3]),
                cvtpk(sa2[4], sa2[5]), cvtpk(sa2[6], sa2[7]));
      }
    }
  }
  __syncthreads();

  // ---------------- inter: acc += psi(Q) · S_prefix ----------------
  f32x4 accC[2][5];
#pragma unroll
  for (int mm = 0; mm < 2; ++mm)
#pragma unroll
    for (int nt = 0; nt < 5; ++nt) accC[mm][nt] = (f32x4){0.f, 0.f, 0.f, 0.f};

  if (c > 0) {
    const float* qrow0 = &sm.qx[s0 * 16 + n16][0];
    const float* qrow1 = &sm.qx[s1 * 16 + n16][0];
    for (int ks = 0; ks < KSTEPS; ++ks) {
      unsigned tvv[8];
#pragma unroll
      for (int i = 0; i < 8; ++i) tvv[i] = sm.tbl[ks * 32 + quad * 8 + i];
      float x0[8], x1[8];
#pragma unroll
      for (int i = 0; i < 8; ++i) {
        int d = tvv[i] & 255, e = (tvv[i] >> 8) & 255;
        x0[i] = qrow0[d] * qrow0[e];
        x1[i] = qrow1[d] * qrow1[e];
      }
      short8 afr0 = pk4(cvtpk(x0[0], x0[1]), cvtpk(x0[2], x0[3]),
                        cvtpk(x0[4], x0[5]), cvtpk(x0[6], x0[7]));
      short8 afr1 = pk4(cvtpk(x1[0], x1[1]), cvtpk(x1[2], x1[3]),
                        cvtpk(x1[4], x1[5]), cvtpk(x1[6], x1[7]));
#pragma unroll
      for (int nt = 0; nt < 5; ++nt) {
        int ncol = nt * 16 + n16;
        short8 b = zero8();
        if (ncol < NZ) b = *(const short8*)(&sm.b.stt[ncol][ks * 32 + quad * 8]);
        accC[0][nt] = __builtin_amdgcn_mfma_f32_16x16x32_bf16(afr0, b, accC[0][nt], 0, 0, 0);
        accC[1][nt] = __builtin_amdgcn_mfma_f32_16x16x32_bf16(afr1, b, accC[1][nt], 0, 0, 0);
      }
    }
  }
  __syncthreads();   // stt fully consumed -> ptile/zline may alias it

  // ---------------- intra: balanced strips; K-frags from kbf (L2-local) --------
  const unsigned short* kbc = kbf + base * D;
  unsigned short* pw = &sm.b.u.ptile[w][0];
  short8 ones;
#pragma unroll
  for (int i = 0; i < 8; ++i) ones[i] = (short)0x3F80;

#pragma unroll
  for (int mm = 0; mm < 2; ++mm) {
    const int s = mm ? s1 : s0;
    const int ntiles = (s >> 1) + 1;
    for (int jt = 0; jt < ntiles; ++jt) {
      short8 kb[2];
#pragma unroll
      for (int ntk = 0; ntk < 2; ++ntk) {
        short8 b = zero8();
        if (quad < 2)
          b = *(const short8*)(kbc + (size_t)(jt * 32 + ntk * 16 + n16) * D + quad * 8);
        kb[ntk] = b;
      }
      f32x4 zf = (f32x4){0.f, 0.f, 0.f, 0.f};
      f32x4 sres[2];
      sres[0] = __builtin_amdgcn_mfma_f32_16x16x32_bf16(qf[mm], kb[0], zf, 0, 0, 0);
      sres[1] = __builtin_amdgcn_mfma_f32_16x16x32_bf16(qf[mm], kb[1], zf, 0, 0, 0);
      const bool last = (jt == ntiles - 1);
#pragma unroll
      for (int ntk = 0; ntk < 2; ++ntk) {
        float ph[4];
#pragma unroll
        for (int r = 0; r < 4; ++r) {
          float sv = sres[ntk][r];
          float phi = fmaf(sv, fmaf(0.5f, sv, 1.0f), 1.0f);  // 1 + s + 0.5 s^2
          if (last) {
            int qrow_g = s * 16 + quad * 4 + r;
            int kcol_g = jt * 32 + ntk * 16 + n16;
            if (kcol_g > qrow_g) phi = 0.f;                  // causal
          }
          ph[r] = phi;
        }
        unsigned u01 = cvtpk(ph[0], ph[1]);
        unsigned u23 = cvtpk(ph[2], ph[3]);
        int rb = (quad * 4) * 40 + ntk * 16 + n16;
        pw[rb      ] = (unsigned short)u01;
        pw[rb +  40] = (unsigned short)(u01 >> 16);
        pw[rb +  80] = (unsigned short)u23;
        pw[rb + 120] = (unsigned short)(u23 >> 16);
      }
      short8 pa = *(const short8*)(pw + n16 * 40 + quad * 8);
#pragma unroll
      for (int nt = 0; nt < 5; ++nt) {
        int ncol = nt * 16 + n16;
        short8 b;
        if (ncol < 64)       b = *(const short8*)(&sm.vt[ncol][jt * 32 + quad * 8]);
        else if (ncol == 64) b = ones;
        else                 b = zero8();
        accC[mm][nt] = __builtin_amdgcn_mfma_f32_16x16x32_bf16(pa, b, accC[mm][nt], 0, 0, 0);
      }
    }
  }

  // epilogue: z broadcast via per-wave LDS rows, normalize, store
  if (n16 == 0) {
#pragma unroll
    for (int mm = 0; mm < 2; ++mm) {
      int s = mm ? s1 : s0;
#pragma unroll
      for (int r = 0; r < 4; ++r)
        sm.b.u.zline[s * 16 + quad * 4 + r] = accC[mm][4][r];
    }
  }
  float* oc = out + base * DV;
#pragma unroll
  for (int mm = 0; mm < 2; ++mm) {
    int s = mm ? s1 : s0;
#pragma unroll
    for (int r = 0; r < 4; ++r) {
      int qrow = s * 16 + quad * 4 + r;
      float inv = __builtin_amdgcn_rcpf(sm.b.u.zline[qrow] + 1e-6f);
#pragma unroll
      for (int nt = 0; nt < 4; ++nt)
        oc[(size_t)qrow * DV + nt * 16 + n16] = accC[mm][nt][r] * inv;
    }
  }
}

extern "C" void kernel_launch(void* const* d_in, const int* in_sizes, int n_in,
                              void* d_out, int out_size, void* d_ws, size_t ws_size,
                              hipStream_t stream) {
  (void)in_sizes; (void)n_in; (void)out_size; (void)ws_size;
  const float* q = (const float*)d_in[0];
  const float* k = (const float*)d_in[1];
  const float* v = (const float*)d_in[2];
  float* out = (float*)d_out;
  char* wsb = (char*)d_ws;
  unsigned*       kbf32 = (unsigned*)(wsb + OFF_KBF);
  unsigned short* kbf   = (unsigned short*)(wsb + OFF_KBF);
  unsigned short* stp   = (unsigned short*)(wsb + OFF_ST);

  pass1<<<BH * NC, 512, 0, stream>>>(k, v, kbf32, stp);
  pass2<<<BH * NC, 512, 0, stream>>>(q, kbf, v, stp, out);
}

// Round 6
// 123.253 us; speedup vs baseline: 1.0935x; 1.0252x over previous
//
#include <hip/hip_runtime.h>
#include <cstddef>

// Problem: b=2,h=16,L=4096,d=16,dv=64, chunk=256. Second-order linear attn.
#define BH    32
#define LSEQ  4096
#define D     16
#define DV    64
#define CS    256
#define NC    16
#define NF    160     // padded feature dim (153 real)
#define NZ    65      // 64 v cols + z col
#define KSTEPS 5      // NF/32
#define PER   (NZ * NF)   // 10400 state elems per (bh, chunk)

typedef short short8 __attribute__((ext_vector_type(8)));
typedef float f32x4 __attribute__((ext_vector_type(4)));
typedef float f4 __attribute__((ext_vector_type(4)));
typedef unsigned uint4v __attribute__((ext_vector_type(4)));

// ws layout (bytes)
#define OFF_KBF 0u                                    // [BH][LSEQ][16] bf16  (4 MiB)
#define OFF_ST  (4u*1024u*1024u)                      // [BH][NC][NZ][NF] bf16 (10.65 MB)

__device__ __forceinline__ float bf2f(unsigned short u) {
  return __uint_as_float(((unsigned)u) << 16);
}
__device__ __forceinline__ short8 zero8() {
  short8 z = {0,0,0,0,0,0,0,0};
  return z;
}
// packed f32x2 -> bf16x2 (RNE), 1 VALU op
__device__ __forceinline__ unsigned cvtpk(float lo, float hi) {
  unsigned r;
  asm("v_cvt_pk_bf16_f32 %0, %1, %2" : "=v"(r) : "v"(lo), "v"(hi));
  return r;
}
__device__ __forceinline__ short8 pk4(unsigned a, unsigned b, unsigned c, unsigned d) {
  uint4v u = {a, b, c, d};
  return __builtin_bit_cast(short8, u);
}

// vt column skew: row f's data column j lives at (j + 8*((f>>2)&7)) mod 256.
// Breaks the 8-way bank conflict of the transposed staging writes (bank =
// 16*(m16&1)+4r+j0/2 -> only 8 banks) into a full-32-bank 2-way pattern, while
// keeping 8-short granules intact (16B-aligned b128 reads still legal).
// Row 64 (ones) has skew 0 -> its write/read paths are unchanged.
__device__ __forceinline__ int vtc(int f, int j) {
  return (j + (((f >> 2) & 7) << 3)) & 255;
}

// feature table: d | (e<<8) | (psi_half?1<<16:0).  qx/kx rows have [16]=1, [17]=0.
__device__ __forceinline__ unsigned feat_tbl(int f) {
  if (f == 0)  return 16u | (16u << 8);                       // const: 1*1
  if (f <= 16) return (unsigned)(f - 1) | (16u << 8);         // linear: x_d * 1
  if (f < 137) {                                              // pairs d<e
    int p = f - 17, off = 0;
    for (int d = 0; d < 15; ++d) {
      int cnt = 15 - d;
      if (p < off + cnt) return (unsigned)d | ((unsigned)(d + 1 + p - off) << 8);
      off += cnt;
    }
  }
  if (f < 153) {                                              // diag: psi=0.5*q_d^2, chi=k_d^2
    int d = f - 137;
    return (unsigned)d | ((unsigned)d << 8) | (1u << 16);
  }
  return 17u | (17u << 8);                                    // pad: 0*0
}

// ============ PASS 1: stage k (kbf bf16 global + fp32 LDS), v^T; state ============
// bh = blk & 31, c = blk >> 5  ->  blk % 8 == bh % 8: all chunks of a bh share an
// XCD, so st/kbf writes here are L2-local for pass2's reads of the same bh.
// c == 15: kbf only (its state is never consumed).
__global__ __launch_bounds__(512, 4) void pass1(const float* __restrict__ k,
                                                const float* __restrict__ v,
                                                unsigned* __restrict__ kbf_u32,
                                                unsigned short* __restrict__ st) {
  __shared__ float kx[CS][18];
  __shared__ __align__(16) unsigned short vt[NZ][264];
  __shared__ unsigned tbl[NF];
  int blk = blockIdx.x, bh = blk & 31, c = blk >> 5;
  int t = threadIdx.x, w = t >> 6, lane = t & 63, quad = lane >> 4, n16 = lane & 15;
  const size_t base = (size_t)bh * LSEQ + (size_t)c * CS;
  (void)lane;

  {
    const f4* K4 = (const f4*)(k + base * D);
    uint2* kbd2 = (uint2*)(kbf_u32 + base * D / 2);
    for (int idx = t; idx < 1024; idx += 512) {
      f4 kv = K4[idx];
      kbd2[idx] = make_uint2(cvtpk(kv[0], kv[1]), cvtpk(kv[2], kv[3]));
      float* dst = &kx[idx >> 2][(idx & 3) * 4];
      *(float2*)dst = make_float2(kv[0], kv[1]);
      *(float2*)(dst + 2) = make_float2(kv[2], kv[3]);
    }
    for (int i = t; i < CS; i += 512) { kx[i][16] = 1.f; kx[i][17] = 0.f; }
  }
  if (c < 15) {
    const f4* V4 = (const f4*)(v + base * DV);
    for (int idx = t; idx < 2048; idx += 512) {
      int m16 = idx & 15, j0 = (idx >> 4) * 2;
      f4 a  = V4[j0 * 16 + m16];
      f4 bq = V4[j0 * 16 + 16 + m16];
#pragma unroll
      for (int r = 0; r < 4; ++r)
        *(unsigned*)&vt[m16 * 4 + r][vtc(m16 * 4 + r, j0)] = cvtpk(a[r], bq[r]);
    }
    if (t < 128) ((unsigned*)&vt[64][0])[t] = 0x3F803F80u;       // ones column (skew 0)
  }
  if (t < NF) tbl[t] = feat_tbl(t);
  __syncthreads();

  if (c < 15) {
    // waves 0,1 own feature-tiles {w, w+8}; waves 2..7 own tile {w}. (10 tiles)
    const int ntt = (w < 2) ? 2 : 1;
    unsigned short* stc = st + (size_t)(bh * NC + c) * PER;
    for (int tt = 0; tt < ntt; ++tt) {
      const int T = tt ? (w + 8) : w;
      unsigned tv = tbl[T * 16 + n16];
      int d0 = tv & 255, e0 = (tv >> 8) & 255;
      f32x4 acc5[5];
#pragma unroll
      for (int nt = 0; nt < 5; ++nt) acc5[nt] = (f32x4){0.f, 0.f, 0.f, 0.f};
      for (int jt = 0; jt < 8; ++jt) {
        float x[8];
#pragma unroll
        for (int i = 0; i < 8; ++i) {
          const float* kr = &kx[jt * 32 + quad * 8 + i][0];
          x[i] = kr[d0] * kr[e0];                        // chi (0.5 folded at store)
        }
        short8 afr = pk4(cvtpk(x[0], x[1]), cvtpk(x[2], x[3]),
                         cvtpk(x[4], x[5]), cvtpk(x[6], x[7]));
#pragma unroll
        for (int nt = 0; nt < 5; ++nt) {
          int ncol = nt * 16 + n16;
          short8 b = zero8();
          if (ncol < NZ)
            b = *(const short8*)(&vt[ncol][vtc(ncol, jt * 32 + quad * 8)]);
          acc5[nt] = __builtin_amdgcn_mfma_f32_16x16x32_bf16(afr, b, acc5[nt], 0, 0, 0);
        }
      }
      const int feat0 = T * 16 + quad * 4;
      float sc[4];
#pragma unroll
      for (int r = 0; r < 4; ++r)
        sc[r] = (feat0 + r >= 137 && feat0 + r < 153) ? 0.5f : 1.0f;  // psi-diag fold
#pragma unroll
      for (int nt = 0; nt < 5; ++nt) {
        int col = nt * 16 + n16;
        if (col < NZ) {
          unsigned lo = cvtpk(acc5[nt][0] * sc[0], acc5[nt][1] * sc[1]);
          unsigned hi = cvtpk(acc5[nt][2] * sc[2], acc5[nt][3] * sc[3]);
          *(uint2*)(stc + (size_t)col * NF + feat0) = make_uint2(lo, hi);
        }
      }
    }
  }
}

// ============ PASS 2: B (prefix) + inter + intra + epilogue ============
// Kernel boundary = the global barrier. Intra strips are the BALANCED pairing
// {w, 15-w}: every wave does exactly 9 key-tiles (the R3 map left here by the
// split gave w2..w7 11 tiles while w0 did 2 -> 11-tile critical path).
struct Smem2 {
  float qx[CS][18];                                     // 18432 B
  __align__(16) unsigned short vt[NZ][264];             // 34320 B
  union {
    __align__(16) unsigned short stt[NZ][168];          // 21840 B (B / inter)
    struct {
      __align__(16) unsigned short ptile[8][640];       // 10240 B (intra)
      float zline[CS];                                  // 1024 B (epilogue)
    } u;
  } b;
  unsigned tbl[NF];                                     // 640 B
};                                                      // total 75232 B

__global__ __launch_bounds__(512, 4) void pass2(const float* __restrict__ q,
                                                const unsigned short* __restrict__ kbf,
                                                const float* __restrict__ v,
                                                const unsigned short* __restrict__ st,
                                                float* __restrict__ out) {
  __shared__ Smem2 sm;
  int blk = blockIdx.x, bh = blk & 31, c = blk >> 5;
  int t = threadIdx.x, w = t >> 6, lane = t & 63, quad = lane >> 4, n16 = lane & 15;
  const size_t base = (size_t)bh * LSEQ + (size_t)c * CS;

  // balanced strips: every wave gets (w/2+1) + ((15-w)/2+1) = 9 key-tiles
  const int s0 = w;
  const int s1 = 15 - w;

  // Q fragments: global -> registers (for intra QK^T)
  short8 qf[2] = {zero8(), zero8()};
  if (quad < 2) {
#pragma unroll
    for (int mm = 0; mm < 2; ++mm) {
      int s = mm ? s1 : s0;
      const f4* qp = (const f4*)(q + (base + (size_t)(s * 16 + n16)) * D + quad * 8);
      f4 qa = qp[0] * 0.25f;
      f4 qb = qp[1] * 0.25f;
      qf[mm] = pk4(cvtpk(qa[0], qa[1]), cvtpk(qa[2], qa[3]),
                   cvtpk(qb[0], qb[1]), cvtpk(qb[2], qb[3]));
    }
  }

  // stage qx (fp32 LDS, *0.25), v^T (bf16 LDS, skewed), tbl
  {
    const f4* Q4 = (const f4*)(q + base * D);
    for (int idx = t; idx < 1024; idx += 512) {
      f4 qv = Q4[idx] * 0.25f;
      float* dst = &sm.qx[idx >> 2][(idx & 3) * 4];
      *(float2*)dst = make_float2(qv[0], qv[1]);
      *(float2*)(dst + 2) = make_float2(qv[2], qv[3]);
    }
    for (int i = t; i < CS; i += 512) { sm.qx[i][16] = 1.f; sm.qx[i][17] = 0.f; }
    const f4* V4 = (const f4*)(v + base * DV);
    for (int idx = t; idx < 2048; idx += 512) {
      int m16 = idx & 15, j0 = (idx >> 4) * 2;
      f4 a  = V4[j0 * 16 + m16];
      f4 bq = V4[j0 * 16 + 16 + m16];
#pragma unroll
      for (int r = 0; r < 4; ++r)
        *(unsigned*)&sm.vt[m16 * 4 + r][vtc(m16 * 4 + r, j0)] = cvtpk(a[r], bq[r]);
    }
    if (t < 128) ((unsigned*)&sm.vt[64][0])[t] = 0x3F803F80u;    // ones column (skew 0)
    if (t < NF) sm.tbl[t] = feat_tbl(t);
  }
  __syncthreads();

  // ---------------- Phase B: pipelined prefix sum into LDS ----------------
  if (c > 0) {
    const unsigned short* stg = st + (size_t)bh * NC * PER;
    float sa0[8], sa1[8], sa2[8];
#pragma unroll
    for (int e = 0; e < 8; ++e) { sa0[e] = 0.f; sa1[e] = 0.f; sa2[e] = 0.f; }
    const int i0 = t * 8, i1 = i0 + 4096, i2 = i0 + 8192;
    const bool h2 = (i2 < PER);
    short8 a0 = *(const short8*)(stg + i0);
    short8 a1 = *(const short8*)(stg + i1);
    short8 a2 = h2 ? *(const short8*)(stg + i2) : zero8();
    for (int cc = 1; cc < c; ++cc) {
      const unsigned short* pn = stg + (size_t)cc * PER;
      short8 b0 = *(const short8*)(pn + i0);             // next-iter loads issued
      short8 b1 = *(const short8*)(pn + i1);             // before current adds
      short8 b2 = h2 ? *(const short8*)(pn + i2) : zero8();
#pragma unroll
      for (int e = 0; e < 8; ++e) {
        sa0[e] += bf2f((unsigned short)a0[e]);
        sa1[e] += bf2f((unsigned short)a1[e]);
        sa2[e] += bf2f((unsigned short)a2[e]);
      }
      a0 = b0; a1 = b1; a2 = b2;
    }
#pragma unroll
    for (int e = 0; e < 8; ++e) {
      sa0[e] += bf2f((unsigned short)a0[e]);
      sa1[e] += bf2f((unsigned short)a1[e]);
      sa2[e] += bf2f((unsigned short)a2[e]);
    }
    {
      int col = i0 / NF, ft = i0 - col * NF;
      *(short8*)(&sm.b.stt[col][ft]) =
          pk4(cvtpk(sa0[0], sa0[1]), cvtpk(sa0[2], sa0[3]),
              cvtpk(sa0[4], sa0[5]), cvtpk(sa0[6], sa0[7]));
      col = i1 / NF; ft = i1 - col * NF;
      *(short8*)(&sm.b.stt[col][ft]) =
          pk4(cvtpk(sa1[0], sa1[1]), cvtpk(sa1[2], sa1[3]),
              cvtpk(sa1[4], sa1[5]), cvtpk(sa1[6], sa1[7]));
      if (h2) {
        col = i2 / NF; ft = i2 - col * NF;
        *(short8*)(&sm.b.stt[col][ft]) =
            pk4(cvtpk(sa2[0], sa2[1]), cvtpk(sa2[2], sa2[3]),
                cvtpk(sa2[4], sa2[5]), cvtpk(sa2[6], sa2[7]));
      }
    }
  }
  __syncthreads();

  // ---------------- inter: acc += psi(Q) · S_prefix ----------------
  f32x4 accC[2][5];
#pragma unroll
  for (int mm = 0; mm < 2; ++mm)
#pragma unroll
    for (int nt = 0; nt < 5; ++nt) accC[mm][nt] = (f32x4){0.f, 0.f, 0.f, 0.f};

  if (c > 0) {
    const float* qrow0 = &sm.qx[s0 * 16 + n16][0];
    const float* qrow1 = &sm.qx[s1 * 16 + n16][0];
    for (int ks = 0; ks < KSTEPS; ++ks) {
      unsigned tvv[8];
#pragma unroll
      for (int i = 0; i < 8; ++i) tvv[i] = sm.tbl[ks * 32 + quad * 8 + i];
      float x0[8], x1[8];
#pragma unroll
      for (int i = 0; i < 8; ++i) {
        int d = tvv[i] & 255, e = (tvv[i] >> 8) & 255;
        x0[i] = qrow0[d] * qrow0[e];
        x1[i] = qrow1[d] * qrow1[e];
      }
      short8 afr0 = pk4(cvtpk(x0[0], x0[1]), cvtpk(x0[2], x0[3]),
                        cvtpk(x0[4], x0[5]), cvtpk(x0[6], x0[7]));
      short8 afr1 = pk4(cvtpk(x1[0], x1[1]), cvtpk(x1[2], x1[3]),
                        cvtpk(x1[4], x1[5]), cvtpk(x1[6], x1[7]));
#pragma unroll
      for (int nt = 0; nt < 5; ++nt) {
        int ncol = nt * 16 + n16;
        short8 b = zero8();
        if (ncol < NZ) b = *(const short8*)(&sm.b.stt[ncol][ks * 32 + quad * 8]);
        accC[0][nt] = __builtin_amdgcn_mfma_f32_16x16x32_bf16(afr0, b, accC[0][nt], 0, 0, 0);
        accC[1][nt] = __builtin_amdgcn_mfma_f32_16x16x32_bf16(afr1, b, accC[1][nt], 0, 0, 0);
      }
    }
  }
  __syncthreads();   // stt fully consumed -> ptile/zline may alias it

  // ---------------- intra: balanced strips; K-frags from kbf (L2-local) --------
  const unsigned short* kbc = kbf + base * D;
  unsigned short* pw = &sm.b.u.ptile[w][0];
  short8 ones;
#pragma unroll
  for (int i = 0; i < 8; ++i) ones[i] = (short)0x3F80;

#pragma unroll
  for (int mm = 0; mm < 2; ++mm) {
    const int s = mm ? s1 : s0;
    const int ntiles = (s >> 1) + 1;
    for (int jt = 0; jt < ntiles; ++jt) {
      short8 kb[2];
#pragma unroll
      for (int ntk = 0; ntk < 2; ++ntk) {
        short8 b = zero8();
        if (quad < 2)
          b = *(const short8*)(kbc + (size_t)(jt * 32 + ntk * 16 + n16) * D + quad * 8);
        kb[ntk] = b;
      }
      f32x4 zf = (f32x4){0.f, 0.f, 0.f, 0.f};
      f32x4 sres[2];
      sres[0] = __builtin_amdgcn_mfma_f32_16x16x32_bf16(qf[mm], kb[0], zf, 0, 0, 0);
      sres[1] = __builtin_amdgcn_mfma_f32_16x16x32_bf16(qf[mm], kb[1], zf, 0, 0, 0);
      const bool last = (jt == ntiles - 1);
#pragma unroll
      for (int ntk = 0; ntk < 2; ++ntk) {
        float ph[4];
#pragma unroll
        for (int r = 0; r < 4; ++r) {
          float sv = sres[ntk][r];
          float phi = fmaf(sv, fmaf(0.5f, sv, 1.0f), 1.0f);  // 1 + s + 0.5 s^2
          if (last) {
            int qrow_g = s * 16 + quad * 4 + r;
            int kcol_g = jt * 32 + ntk * 16 + n16;
            if (kcol_g > qrow_g) phi = 0.f;                  // causal
          }
          ph[r] = phi;
        }
        unsigned u01 = cvtpk(ph[0], ph[1]);
        unsigned u23 = cvtpk(ph[2], ph[3]);
        int rb = (quad * 4) * 40 + ntk * 16 + n16;
        pw[rb      ] = (unsigned short)u01;
        pw[rb +  40] = (unsigned short)(u01 >> 16);
        pw[rb +  80] = (unsigned short)u23;
        pw[rb + 120] = (unsigned short)(u23 >> 16);
      }
      short8 pa = *(const short8*)(pw + n16 * 40 + quad * 8);
#pragma unroll
      for (int nt = 0; nt < 5; ++nt) {
        int ncol = nt * 16 + n16;
        short8 b;
        if (ncol < 64)
          b = *(const short8*)(&sm.vt[ncol][vtc(ncol, jt * 32 + quad * 8)]);
        else if (ncol == 64) b = ones;
        else                 b = zero8();
        accC[mm][nt] = __builtin_amdgcn_mfma_f32_16x16x32_bf16(pa, b, accC[mm][nt], 0, 0, 0);
      }
    }
  }

  // epilogue: z broadcast via per-wave LDS rows, normalize, store
  if (n16 == 0) {
#pragma unroll
    for (int mm = 0; mm < 2; ++mm) {
      int s = mm ? s1 : s0;
#pragma unroll
      for (int r = 0; r < 4; ++r)
        sm.b.u.zline[s * 16 + quad * 4 + r] = accC[mm][4][r];
    }
  }
  float* oc = out + base * DV;
#pragma unroll
  for (int mm = 0; mm < 2; ++mm) {
    int s = mm ? s1 : s0;
#pragma unroll
    for (int r = 0; r < 4; ++r) {
      int qrow = s * 16 + quad * 4 + r;
      float inv = __builtin_amdgcn_rcpf(sm.b.u.zline[qrow] + 1e-6f);
#pragma unroll
      for (int nt = 0; nt < 4; ++nt)
        oc[(size_t)qrow * DV + nt * 16 + n16] = accC[mm][nt][r] * inv;
    }
  }
}

extern "C" void kernel_launch(void* const* d_in, const int* in_sizes, int n_in,
                              void* d_out, int out_size, void* d_ws, size_t ws_size,
                              hipStream_t stream) {
  (void)in_sizes; (void)n_in; (void)out_size; (void)ws_size;
  const float* q = (const float*)d_in[0];
  const float* k = (const float*)d_in[1];
  const float* v = (const float*)d_in[2];
  float* out = (float*)d_out;
  char* wsb = (char*)d_ws;
  unsigned*       kbf32 = (unsigned*)(wsb + OFF_KBF);
  unsigned short* kbf   = (unsigned short*)(wsb + OFF_KBF);
  unsigned short* stp   = (unsigned short*)(wsb + OFF_ST);

  pass1<<<BH * NC, 512, 0, stream>>>(k, v, kbf32, stp);
  pass2<<<BH * NC, 512, 0, stream>>>(q, kbf, v, stp, out);
}